// Round 1
// baseline (95.129 us; speedup 1.0000x reference)
//
#include <hip/hip_runtime.h>
#include <hip/hip_bf16.h>

typedef __attribute__((ext_vector_type(8))) short short8;
typedef __attribute__((ext_vector_type(4))) float f32x4;

#define NP_TOTAL 196608   // (1024*16) * 12 positions
#define MT 32             // positions per block
#define BLK 256

// LDS layout (byte offsets). All tiles row-swizzled: byte ^= ((row&7)<<4)
#define A1_OFF   0        // 32 rows x 1024B  (512 bf16 per row)  = 32768
#define PART_OFF 32768    // 32 rows x 128B   (32 fp32 per row)   =  4096
#define A2_OFF   36864    // 32 rows x 128B   (64 bf16 per row)   =  4096
#define A3_OFF   40960    // 32 rows x 128B   (32 bf16 used/row)  =  4096
#define XS_OFF   45056    // 32 x 16 fp32                          =  2048
#define SMEM_BYTES 47104

// workspace layout (bytes)
#define WS_B1F   0        // float[64]
#define WS_B2F   256      // float[32]
#define WS_W1F   512      // bf16[32768] frag-ordered
#define WS_W2F   66048    // bf16[2048]  frag-ordered
#define WS_W3F   70144    // bf16[1024]  frag-ordered

__global__ void prep_kernel(
    const float* __restrict__ w1, const float* __restrict__ b1,
    const float* __restrict__ g1, const float* __restrict__ bt1,
    const float* __restrict__ m1, const float* __restrict__ v1,
    const float* __restrict__ w2, const float* __restrict__ b2,
    const float* __restrict__ g2, const float* __restrict__ bt2,
    const float* __restrict__ m2, const float* __restrict__ v2,
    const float* __restrict__ w3,
    float* __restrict__ bias1f, float* __restrict__ bias2f,
    __hip_bfloat16* __restrict__ W1f, __hip_bfloat16* __restrict__ W2f,
    __hip_bfloat16* __restrict__ W3f)
{
    int t  = blockIdx.x * blockDim.x + threadIdx.x;
    int nt = gridDim.x * blockDim.x;
    if (t < 64)            { float s = g1[t] / sqrtf(v1[t] + 1e-5f); bias1f[t] = (b1[t] - m1[t]) * s + bt1[t]; }
    if (t >= 64 && t < 96) { int o = t - 64; float s = g2[o] / sqrtf(v2[o] + 1e-5f); bias2f[o] = (b2[o] - m2[o]) * s + bt2[o]; }
    // W1 frag order: [ct(4)][kk(16)][lane(64)][j(8)], B[k][n] = s1[n]*w1[n][k]
    for (int fi = t; fi < 64 * 512; fi += nt) {
        int j = fi & 7, lane = (fi >> 3) & 63, kt = fi >> 9;   // kt = ct*16+kk
        int ct = kt >> 4, kk = kt & 15;
        int k = kk * 32 + ((lane >> 4) << 3) + j;
        int n = ct * 16 + (lane & 15);
        float s = g1[n] / sqrtf(v1[n] + 1e-5f);
        W1f[fi] = __float2bfloat16(s * w1[n * 512 + k]);
    }
    // W2 frag order: [ct(2)][kk(2)][lane][j]
    for (int fi = t; fi < 2048; fi += nt) {
        int j = fi & 7, lane = (fi >> 3) & 63, kt = fi >> 9;   // kt = ct*2+kk
        int ct = kt >> 1, kk = kt & 1;
        int k = kk * 32 + ((lane >> 4) << 3) + j;
        int n = ct * 16 + (lane & 15);
        float s = g2[n] / sqrtf(v2[n] + 1e-5f);
        W2f[fi] = __float2bfloat16(s * w2[n * 64 + k]);
    }
    // W3 frag order: [ct(2)][lane][j]
    for (int fi = t; fi < 1024; fi += nt) {
        int j = fi & 7, lane = (fi >> 3) & 63, ct = fi >> 9;
        int k = ((lane >> 4) << 3) + j;
        int n = ct * 16 + (lane & 15);
        W3f[fi] = __float2bfloat16(w3[n * 32 + k]);
    }
}

__global__ __launch_bounds__(BLK) void fused_kernel(
    const float* __restrict__ x,
    const float* __restrict__ cat_emb, const float* __restrict__ cat_lin,
    const float* __restrict__ cont_w,  const float* __restrict__ cont_b,
    const float* __restrict__ cont_lw, const float* __restrict__ cont_lb,
    const float* __restrict__ fin_bias,
    const float* __restrict__ bias1f,  const float* __restrict__ bias2f,
    const float* __restrict__ out_b,
    const __hip_bfloat16* __restrict__ W1f,
    const __hip_bfloat16* __restrict__ W2f,
    const __hip_bfloat16* __restrict__ W3f,
    float* __restrict__ out)
{
    __shared__ __align__(16) char smem[SMEM_BYTES];
    const int tid  = threadIdx.x;
    const int lane = tid & 63;
    const int wv   = tid >> 6;

    // ---- stage x slice (32 pos x 16 feat, contiguous) ----
    {
        const float2* xb = (const float2*)(x + (size_t)blockIdx.x * (MT * 16));
        ((float2*)(smem + XS_OFF))[tid] = xb[tid];
    }
    __syncthreads();

    // ---- Phase A: embeddings, FM + linear (fp32), A1 tile (bf16) ----
    {
        const float* xs = (const float*)(smem + XS_OFF);
        const int d = tid & 31, pg = tid >> 5;
        float finb = fin_bias[d];
        #pragma unroll
        for (int i = 0; i < 4; ++i) {
            int p = pg + 8 * i;
            const float* xp = xs + p * 16;
            float ssum = 0.f, ssq = 0.f, lin = finb;
            #pragma unroll
            for (int f = 0; f < 8; ++f) {
                int ix = (int)xp[f];
                float e  = cat_emb[(f * 1000 + ix) * 32 + d];
                float el = cat_lin[(f * 1000 + ix) * 32 + d];
                ssum += e; ssq += e * e; lin += el;
                *(__hip_bfloat16*)(smem + A1_OFF + ((p * 1024 + (f * 32 + d) * 2) ^ ((p & 7) << 4)))
                    = __float2bfloat16(e);
            }
            #pragma unroll
            for (int f = 0; f < 8; ++f) {
                float c  = xp[8 + f];
                float e  = fmaf(c, cont_w[f * 32 + d],  cont_b[f * 32 + d]);
                float el = fmaf(c, cont_lw[f * 32 + d], cont_lb[f * 32 + d]);
                ssum += e; ssq += e * e; lin += el;
                *(__hip_bfloat16*)(smem + A1_OFF + ((p * 1024 + ((8 + f) * 32 + d) * 2) ^ ((p & 7) << 4)))
                    = __float2bfloat16(e);
            }
            *(float*)(smem + PART_OFF + ((p * 128 + d * 4) ^ ((p & 7) << 4)))
                = lin + 0.5f * (ssum * ssum - ssq);
        }
    }
    __syncthreads();

    const int akb = (lane >> 4) << 3;   // k sub-offset within fragment

    // ---- GEMM1: (32 x 512) x (512 x 64); wave: rt=wv&1, cts {wv>>1, wv>>1+2} ----
    const short8* W1v = (const short8*)W1f;
    int rt1  = wv & 1;
    int ct1a = wv >> 1, ct1b = (wv >> 1) + 2;
    f32x4 acc0 = {0.f, 0.f, 0.f, 0.f}, acc1 = {0.f, 0.f, 0.f, 0.f};
    int arow1 = rt1 * 16 + (lane & 15);
    #pragma unroll
    for (int kk = 0; kk < 16; ++kk) {
        short8 a  = *(const short8*)(smem + A1_OFF + ((arow1 * 1024 + (kk * 32 + akb) * 2) ^ ((arow1 & 7) << 4)));
        short8 b0 = W1v[(ct1a * 16 + kk) * 64 + lane];
        short8 b1 = W1v[(ct1b * 16 + kk) * 64 + lane];
        acc0 = __builtin_amdgcn_mfma_f32_16x16x32_bf16(a, b0, acc0, 0, 0, 0);
        acc1 = __builtin_amdgcn_mfma_f32_16x16x32_bf16(a, b1, acc1, 0, 0, 0);
    }
    // h1 = relu(acc + bias1f) -> A2 (bf16, swizzled)
    {
        float bo0 = bias1f[ct1a * 16 + (lane & 15)];
        float bo1 = bias1f[ct1b * 16 + (lane & 15)];
        int o0 = ct1a * 16 + (lane & 15), o1 = ct1b * 16 + (lane & 15);
        int pb = rt1 * 16 + ((lane >> 4) << 2);
        #pragma unroll
        for (int r = 0; r < 4; ++r) {
            int p = pb + r;
            float h0 = fmaxf(acc0[r] + bo0, 0.f);
            float h1 = fmaxf(acc1[r] + bo1, 0.f);
            *(__hip_bfloat16*)(smem + A2_OFF + ((p * 128 + o0 * 2) ^ ((p & 7) << 4))) = __float2bfloat16(h0);
            *(__hip_bfloat16*)(smem + A2_OFF + ((p * 128 + o1 * 2) ^ ((p & 7) << 4))) = __float2bfloat16(h1);
        }
    }
    __syncthreads();

    // ---- GEMM2: (32 x 64) x (64 x 32); wave: rt2=wv>>1, ct2=wv&1 ----
    const short8* W2v = (const short8*)W2f;
    int rt2 = wv >> 1, ct2 = wv & 1;
    f32x4 acc2 = {0.f, 0.f, 0.f, 0.f};
    int arow2 = rt2 * 16 + (lane & 15);
    #pragma unroll
    for (int kk = 0; kk < 2; ++kk) {
        short8 a = *(const short8*)(smem + A2_OFF + ((arow2 * 128 + (kk * 32 + akb) * 2) ^ ((arow2 & 7) << 4)));
        short8 b = W2v[(ct2 * 2 + kk) * 64 + lane];
        acc2 = __builtin_amdgcn_mfma_f32_16x16x32_bf16(a, b, acc2, 0, 0, 0);
    }
    {
        float bo = bias2f[ct2 * 16 + (lane & 15)];
        int o = ct2 * 16 + (lane & 15);
        int pb = rt2 * 16 + ((lane >> 4) << 2);
        #pragma unroll
        for (int r = 0; r < 4; ++r) {
            int p = pb + r;
            float h = fmaxf(acc2[r] + bo, 0.f);
            *(__hip_bfloat16*)(smem + A3_OFF + ((p * 128 + o * 2) ^ ((p & 7) << 4))) = __float2bfloat16(h);
        }
    }
    __syncthreads();

    // ---- GEMM3: (32 x 32) x (32 x 32); wave: rt3=wv>>1, ct3=wv&1 ----
    const short8* W3v = (const short8*)W3f;
    int rt3 = wv >> 1, ct3 = wv & 1;
    int arow3 = rt3 * 16 + (lane & 15);
    short8 a3 = *(const short8*)(smem + A3_OFF + ((arow3 * 128 + akb * 2) ^ ((arow3 & 7) << 4)));
    short8 b3 = W3v[ct3 * 64 + lane];
    f32x4 z = {0.f, 0.f, 0.f, 0.f};
    f32x4 acc3 = __builtin_amdgcn_mfma_f32_16x16x32_bf16(a3, b3, z, 0, 0, 0);

    // ---- epilogue: out = partial(FM+linear) + dnn_out + out_b ----
    {
        int dcol = ct3 * 16 + (lane & 15);
        float ob = out_b[dcol];
        int pb = rt3 * 16 + ((lane >> 4) << 2);
        size_t outbase = (size_t)blockIdx.x * (MT * 32);
        #pragma unroll
        for (int r = 0; r < 4; ++r) {
            int p = pb + r;
            float part = *(const float*)(smem + PART_OFF + ((p * 128 + dcol * 4) ^ ((p & 7) << 4)));
            out[outbase + p * 32 + dcol] = part + ob + acc3[r];
        }
    }
}

extern "C" void kernel_launch(void* const* d_in, const int* in_sizes, int n_in,
                              void* d_out, int out_size, void* d_ws, size_t ws_size,
                              hipStream_t stream) {
    const float* x        = (const float*)d_in[0];
    const float* cat_emb  = (const float*)d_in[1];
    const float* cat_lin  = (const float*)d_in[2];
    const float* cont_w   = (const float*)d_in[3];
    const float* cont_b   = (const float*)d_in[4];
    const float* cont_lw  = (const float*)d_in[5];
    const float* cont_lb  = (const float*)d_in[6];
    const float* fin_bias = (const float*)d_in[7];
    const float* dnn1_w   = (const float*)d_in[8];
    const float* dnn1_b   = (const float*)d_in[9];
    const float* bn1_g    = (const float*)d_in[10];
    const float* bn1_bt   = (const float*)d_in[11];
    const float* bn1_m    = (const float*)d_in[12];
    const float* bn1_v    = (const float*)d_in[13];
    const float* dnn2_w   = (const float*)d_in[14];
    const float* dnn2_b   = (const float*)d_in[15];
    const float* bn2_g    = (const float*)d_in[16];
    const float* bn2_bt   = (const float*)d_in[17];
    const float* bn2_m    = (const float*)d_in[18];
    const float* bn2_v    = (const float*)d_in[19];
    const float* out_w    = (const float*)d_in[20];
    const float* out_b    = (const float*)d_in[21];

    char* ws = (char*)d_ws;
    float* bias1f = (float*)(ws + WS_B1F);
    float* bias2f = (float*)(ws + WS_B2F);
    __hip_bfloat16* W1f = (__hip_bfloat16*)(ws + WS_W1F);
    __hip_bfloat16* W2f = (__hip_bfloat16*)(ws + WS_W2F);
    __hip_bfloat16* W3f = (__hip_bfloat16*)(ws + WS_W3F);

    hipLaunchKernelGGL(prep_kernel, dim3(128), dim3(BLK), 0, stream,
                       dnn1_w, dnn1_b, bn1_g, bn1_bt, bn1_m, bn1_v,
                       dnn2_w, dnn2_b, bn2_g, bn2_bt, bn2_m, bn2_v,
                       out_w, bias1f, bias2f, W1f, W2f, W3f);

    hipLaunchKernelGGL(fused_kernel, dim3(NP_TOTAL / MT), dim3(BLK), 0, stream,
                       x, cat_emb, cat_lin, cont_w, cont_b, cont_lw, cont_lb,
                       fin_bias, bias1f, bias2f, out_b, W1f, W2f, W3f,
                       (float*)d_out);
}

// Round 2
// 79.611 us; speedup vs baseline: 1.1949x; 1.1949x over previous
//
#include <hip/hip_runtime.h>
#include <hip/hip_bf16.h>

typedef __attribute__((ext_vector_type(8))) short short8;
typedef __attribute__((ext_vector_type(4))) float f32x4;
typedef __attribute__((ext_vector_type(4))) unsigned short ushort4n;

#define NP_TOTAL 196608   // (1024*16) * 12 positions
#define MT 32             // positions per block
#define BLK 256

// LDS layout (byte offsets). Tiles row-swizzled: byte ^= ((row&7)<<4)
// A2/A3 alias the A1 region (A1 dead after GEMM1 reads; barrier inserted).
#define A1_OFF   0        // 32 rows x 1024B (512 bf16/row) = 32768
#define A2_OFF   0        // 32 rows x 128B  (64 bf16/row)  =  4096 (aliases A1)
#define A3_OFF   4096     // 32 rows x 128B                  =  4096 (aliases A1)
#define PART_OFF 32768    // 32 rows x 128B  (32 fp32/row)  =  4096
#define XS_OFF   36864    // 32 x 16 fp32                    =  2048
#define SMEM_BYTES 38912  // -> 4 blocks/CU

// workspace layout (bytes)
#define WS_B1F   0        // float[64]
#define WS_B2F   256      // float[32]
#define WS_W1F   512      // bf16[32768] frag-ordered
#define WS_W2F   66048    // bf16[2048]  frag-ordered
#define WS_W3F   70144    // bf16[1024]  frag-ordered
#define WS_EL    73728    // float2[256000] interleaved (cat_emb, cat_lin)

__global__ void prep_kernel(
    const float* __restrict__ w1, const float* __restrict__ b1,
    const float* __restrict__ g1, const float* __restrict__ bt1,
    const float* __restrict__ m1, const float* __restrict__ v1,
    const float* __restrict__ w2, const float* __restrict__ b2,
    const float* __restrict__ g2, const float* __restrict__ bt2,
    const float* __restrict__ m2, const float* __restrict__ v2,
    const float* __restrict__ w3,
    const float* __restrict__ cat_emb, const float* __restrict__ cat_lin,
    float* __restrict__ bias1f, float* __restrict__ bias2f,
    __hip_bfloat16* __restrict__ W1f, __hip_bfloat16* __restrict__ W2f,
    __hip_bfloat16* __restrict__ W3f, float2* __restrict__ EL)
{
    int t  = blockIdx.x * blockDim.x + threadIdx.x;
    int nt = gridDim.x * blockDim.x;
    if (t < 64)            { float s = g1[t] / sqrtf(v1[t] + 1e-5f); bias1f[t] = (b1[t] - m1[t]) * s + bt1[t]; }
    if (t >= 64 && t < 96) { int o = t - 64; float s = g2[o] / sqrtf(v2[o] + 1e-5f); bias2f[o] = (b2[o] - m2[o]) * s + bt2[o]; }
    // interleaved embedding/linear table: EL[i] = (cat_emb[i], cat_lin[i])
    for (int i = t; i < 8 * 1000 * 32; i += nt) {
        float2 v; v.x = cat_emb[i]; v.y = cat_lin[i];
        EL[i] = v;
    }
    // W1 frag order: [ct(4)][kk(16)][lane(64)][j(8)], B[k][n] = s1[n]*w1[n][k]
    for (int fi = t; fi < 64 * 512; fi += nt) {
        int j = fi & 7, lane = (fi >> 3) & 63, kt = fi >> 9;
        int ct = kt >> 4, kk = kt & 15;
        int k = kk * 32 + ((lane >> 4) << 3) + j;
        int n = ct * 16 + (lane & 15);
        float s = g1[n] / sqrtf(v1[n] + 1e-5f);
        W1f[fi] = __float2bfloat16(s * w1[n * 512 + k]);
    }
    // W2 frag order: [ct(2)][kk(2)][lane][j]
    for (int fi = t; fi < 2048; fi += nt) {
        int j = fi & 7, lane = (fi >> 3) & 63, kt = fi >> 9;
        int ct = kt >> 1, kk = kt & 1;
        int k = kk * 32 + ((lane >> 4) << 3) + j;
        int n = ct * 16 + (lane & 15);
        float s = g2[n] / sqrtf(v2[n] + 1e-5f);
        W2f[fi] = __float2bfloat16(s * w2[n * 64 + k]);
    }
    // W3 frag order: [ct(2)][lane][j]
    for (int fi = t; fi < 1024; fi += nt) {
        int j = fi & 7, lane = (fi >> 3) & 63, ct = fi >> 9;
        int k = ((lane >> 4) << 3) + j;
        int n = ct * 16 + (lane & 15);
        W3f[fi] = __float2bfloat16(w3[n * 32 + k]);
    }
}

static __device__ __forceinline__ unsigned short bf16bits(float f) {
    __hip_bfloat16 h = __float2bfloat16(f);
    return *(unsigned short*)&h;
}

__global__ __launch_bounds__(BLK) void fused_kernel(
    const float* __restrict__ x,
    const float* __restrict__ cont_w,  const float* __restrict__ cont_b,
    const float* __restrict__ cont_lw, const float* __restrict__ cont_lb,
    const float* __restrict__ fin_bias,
    const float* __restrict__ bias1f,  const float* __restrict__ bias2f,
    const float* __restrict__ out_b,
    const __hip_bfloat16* __restrict__ W1f,
    const __hip_bfloat16* __restrict__ W2f,
    const __hip_bfloat16* __restrict__ W3f,
    const float2* __restrict__ EL,
    float* __restrict__ out)
{
    __shared__ __align__(16) char smem[SMEM_BYTES];
    const int tid  = threadIdx.x;
    const int lane = tid & 63;
    const int wv   = tid >> 6;

    // ---- stage x slice (32 pos x 16 feat, contiguous) ----
    if (tid < 128) {
        const float4* xb = (const float4*)(x + (size_t)blockIdx.x * (MT * 16));
        ((float4*)(smem + XS_OFF))[tid] = xb[tid];
    }
    __syncthreads();

    // ---- Phase A: one thread = (position, 4-d group) ----
    {
        const int p = tid >> 3, d0 = (tid & 7) << 2;
        const float* xp = (const float*)(smem + XS_OFF) + p * 16;
        float4 ssum = {0.f, 0.f, 0.f, 0.f}, ssq = {0.f, 0.f, 0.f, 0.f};
        float4 lin = *(const float4*)(fin_bias + d0);
        const int swz = (p & 7) << 4;
        char* arow = smem + A1_OFF + p * 1024;

        #pragma unroll
        for (int f = 0; f < 8; ++f) {
            int ix = (int)xp[f];
            const float4* src = (const float4*)(EL + ((f * 1000 + ix) * 32 + d0));
            float4 v0 = src[0];                    // (e[d0],l[d0],e[d0+1],l[d0+1])
            float4 v1 = src[1];                    // (e[d0+2],l[d0+2],e[d0+3],l[d0+3])
            float4 e  = {v0.x, v0.z, v1.x, v1.z};
            float4 el = {v0.y, v0.w, v1.y, v1.w};
            ssum += e; ssq += e * e; lin += el;
            ushort4n ev = {bf16bits(e.x), bf16bits(e.y), bf16bits(e.z), bf16bits(e.w)};
            *(ushort4n*)(arow + (((f * 32 + d0) * 2) ^ swz)) = ev;
        }
        #pragma unroll
        for (int f = 0; f < 8; ++f) {
            float c  = xp[8 + f];
            float4 w  = *(const float4*)(cont_w  + f * 32 + d0);
            float4 b  = *(const float4*)(cont_b  + f * 32 + d0);
            float4 lw = *(const float4*)(cont_lw + f * 32 + d0);
            float4 lb = *(const float4*)(cont_lb + f * 32 + d0);
            float4 e, el;
            e.x = fmaf(c, w.x, b.x);  e.y = fmaf(c, w.y, b.y);
            e.z = fmaf(c, w.z, b.z);  e.w = fmaf(c, w.w, b.w);
            el.x = fmaf(c, lw.x, lb.x); el.y = fmaf(c, lw.y, lb.y);
            el.z = fmaf(c, lw.z, lb.z); el.w = fmaf(c, lw.w, lb.w);
            ssum += e; ssq += e * e; lin += el;
            ushort4n ev = {bf16bits(e.x), bf16bits(e.y), bf16bits(e.z), bf16bits(e.w)};
            *(ushort4n*)(arow + ((((8 + f) * 32 + d0) * 2) ^ swz)) = ev;
        }
        float4 part;
        part.x = lin.x + 0.5f * (ssum.x * ssum.x - ssq.x);
        part.y = lin.y + 0.5f * (ssum.y * ssum.y - ssq.y);
        part.z = lin.z + 0.5f * (ssum.z * ssum.z - ssq.z);
        part.w = lin.w + 0.5f * (ssum.w * ssum.w - ssq.w);
        *(float4*)(smem + PART_OFF + ((p * 128 + d0 * 4) ^ swz)) = part;
    }
    __syncthreads();

    const int akb = (lane >> 4) << 3;   // k sub-offset within fragment

    // ---- GEMM1: (32 x 512) x (512 x 64); wave: rt=wv&1, cts {wv>>1, wv>>1+2} ----
    const short8* W1v = (const short8*)W1f;
    int rt1  = wv & 1;
    int ct1a = wv >> 1, ct1b = (wv >> 1) + 2;
    f32x4 acc0 = {0.f, 0.f, 0.f, 0.f}, acc1 = {0.f, 0.f, 0.f, 0.f};
    int arow1 = rt1 * 16 + (lane & 15);
    #pragma unroll
    for (int kk = 0; kk < 16; ++kk) {
        short8 a  = *(const short8*)(smem + A1_OFF + ((arow1 * 1024 + (kk * 32 + akb) * 2) ^ ((arow1 & 7) << 4)));
        short8 b0 = W1v[(ct1a * 16 + kk) * 64 + lane];
        short8 b1 = W1v[(ct1b * 16 + kk) * 64 + lane];
        acc0 = __builtin_amdgcn_mfma_f32_16x16x32_bf16(a, b0, acc0, 0, 0, 0);
        acc1 = __builtin_amdgcn_mfma_f32_16x16x32_bf16(a, b1, acc1, 0, 0, 0);
    }
    __syncthreads();   // A1 fully consumed; A2 may now overwrite its region

    // h1 = relu(acc + bias1f) -> A2 (bf16, swizzled)
    {
        float bo0 = bias1f[ct1a * 16 + (lane & 15)];
        float bo1 = bias1f[ct1b * 16 + (lane & 15)];
        int o0 = ct1a * 16 + (lane & 15), o1 = ct1b * 16 + (lane & 15);
        int pb = rt1 * 16 + ((lane >> 4) << 2);
        #pragma unroll
        for (int r = 0; r < 4; ++r) {
            int p = pb + r;
            float h0 = fmaxf(acc0[r] + bo0, 0.f);
            float h1 = fmaxf(acc1[r] + bo1, 0.f);
            *(__hip_bfloat16*)(smem + A2_OFF + ((p * 128 + o0 * 2) ^ ((p & 7) << 4))) = __float2bfloat16(h0);
            *(__hip_bfloat16*)(smem + A2_OFF + ((p * 128 + o1 * 2) ^ ((p & 7) << 4))) = __float2bfloat16(h1);
        }
    }
    __syncthreads();

    // ---- GEMM2: (32 x 64) x (64 x 32); wave: rt2=wv>>1, ct2=wv&1 ----
    const short8* W2v = (const short8*)W2f;
    int rt2 = wv >> 1, ct2 = wv & 1;
    f32x4 acc2 = {0.f, 0.f, 0.f, 0.f};
    int arow2 = rt2 * 16 + (lane & 15);
    #pragma unroll
    for (int kk = 0; kk < 2; ++kk) {
        short8 a = *(const short8*)(smem + A2_OFF + ((arow2 * 128 + (kk * 32 + akb) * 2) ^ ((arow2 & 7) << 4)));
        short8 b = W2v[(ct2 * 2 + kk) * 64 + lane];
        acc2 = __builtin_amdgcn_mfma_f32_16x16x32_bf16(a, b, acc2, 0, 0, 0);
    }
    {
        float bo = bias2f[ct2 * 16 + (lane & 15)];
        int o = ct2 * 16 + (lane & 15);
        int pb = rt2 * 16 + ((lane >> 4) << 2);
        #pragma unroll
        for (int r = 0; r < 4; ++r) {
            int p = pb + r;
            float h = fmaxf(acc2[r] + bo, 0.f);
            *(__hip_bfloat16*)(smem + A3_OFF + ((p * 128 + o * 2) ^ ((p & 7) << 4))) = __float2bfloat16(h);
        }
    }
    __syncthreads();

    // ---- GEMM3: (32 x 32) x (32 x 32) ----
    const short8* W3v = (const short8*)W3f;
    int rt3 = wv >> 1, ct3 = wv & 1;
    int arow3 = rt3 * 16 + (lane & 15);
    short8 a3 = *(const short8*)(smem + A3_OFF + ((arow3 * 128 + akb * 2) ^ ((arow3 & 7) << 4)));
    short8 b3 = W3v[ct3 * 64 + lane];
    f32x4 z = {0.f, 0.f, 0.f, 0.f};
    f32x4 acc3 = __builtin_amdgcn_mfma_f32_16x16x32_bf16(a3, b3, z, 0, 0, 0);

    // ---- epilogue: out = partial(FM+linear) + dnn_out + out_b ----
    {
        int dcol = ct3 * 16 + (lane & 15);
        float ob = out_b[dcol];
        int pb = rt3 * 16 + ((lane >> 4) << 2);
        size_t outbase = (size_t)blockIdx.x * (MT * 32);
        #pragma unroll
        for (int r = 0; r < 4; ++r) {
            int p = pb + r;
            float part = *(const float*)(smem + PART_OFF + ((p * 128 + dcol * 4) ^ ((p & 7) << 4)));
            out[outbase + p * 32 + dcol] = part + ob + acc3[r];
        }
    }
}

extern "C" void kernel_launch(void* const* d_in, const int* in_sizes, int n_in,
                              void* d_out, int out_size, void* d_ws, size_t ws_size,
                              hipStream_t stream) {
    const float* x        = (const float*)d_in[0];
    const float* cat_emb  = (const float*)d_in[1];
    const float* cat_lin  = (const float*)d_in[2];
    const float* cont_w   = (const float*)d_in[3];
    const float* cont_b   = (const float*)d_in[4];
    const float* cont_lw  = (const float*)d_in[5];
    const float* cont_lb  = (const float*)d_in[6];
    const float* fin_bias = (const float*)d_in[7];
    const float* dnn1_w   = (const float*)d_in[8];
    const float* dnn1_b   = (const float*)d_in[9];
    const float* bn1_g    = (const float*)d_in[10];
    const float* bn1_bt   = (const float*)d_in[11];
    const float* bn1_m    = (const float*)d_in[12];
    const float* bn1_v    = (const float*)d_in[13];
    const float* dnn2_w   = (const float*)d_in[14];
    const float* dnn2_b   = (const float*)d_in[15];
    const float* bn2_g    = (const float*)d_in[16];
    const float* bn2_bt   = (const float*)d_in[17];
    const float* bn2_m    = (const float*)d_in[18];
    const float* bn2_v    = (const float*)d_in[19];
    const float* out_w    = (const float*)d_in[20];
    const float* out_b    = (const float*)d_in[21];

    char* ws = (char*)d_ws;
    float* bias1f = (float*)(ws + WS_B1F);
    float* bias2f = (float*)(ws + WS_B2F);
    __hip_bfloat16* W1f = (__hip_bfloat16*)(ws + WS_W1F);
    __hip_bfloat16* W2f = (__hip_bfloat16*)(ws + WS_W2F);
    __hip_bfloat16* W3f = (__hip_bfloat16*)(ws + WS_W3F);
    float2* EL = (float2*)(ws + WS_EL);

    hipLaunchKernelGGL(prep_kernel, dim3(256), dim3(BLK), 0, stream,
                       dnn1_w, dnn1_b, bn1_g, bn1_bt, bn1_m, bn1_v,
                       dnn2_w, dnn2_b, bn2_g, bn2_bt, bn2_m, bn2_v,
                       out_w, cat_emb, cat_lin, bias1f, bias2f, W1f, W2f, W3f, EL);

    hipLaunchKernelGGL(fused_kernel, dim3(NP_TOTAL / MT), dim3(BLK), 0, stream,
                       x, cont_w, cont_b, cont_lw, cont_lb,
                       fin_bias, bias1f, bias2f, out_b, W1f, W2f, W3f, EL,
                       (float*)d_out);
}